// Round 8
// baseline (286.388 us; speedup 1.0000x reference)
//
#include <hip/hip_runtime.h>
#include <hip/hip_bf16.h>

#define N_ 32
#define C_ 64
#define H_ 128
#define W_ 128
#define HW_ (H_ * W_)
#define CHW_ (C_ * HW_)

#define XT_STRIDE 72           // halfs per row (144 B, 16B-aligned); row = w+9, col = channel
#define XT_ROWS 146
#define CB_STRIDE 132          // floats per conv-buffer row (528 B = 16B-aligned!)
#define SMEM_BYTES (64 * CB_STRIDE * 4)   // 33792 >= 146*72*2 = 21024 (union with xT)

typedef __bf16 bf16x8 __attribute__((ext_vector_type(8)));
typedef float floatx4 __attribute__((ext_vector_type(4)));

__device__ inline unsigned short f2bf(float f) {
    __hip_bfloat16 h = __float2bfloat16(f);
    return *reinterpret_cast<unsigned short*>(&h);
}

// Pre-pack weights into MFMA A-fragment order (bf16).
// A[o][k], k = t*64 + i, from Wc[o*448 + i*7 + t].
__global__ void prepack_kernel(const float* __restrict__ Wc, uint4* __restrict__ Ap) {
    int idx = blockIdx.x * 256 + threadIdx.x;
    if (idx >= 14 * 4 * 64) return;
    int lane = idx & 63;
    int mt = (idx >> 6) & 3;
    int kt = idx >> 8;
    int m = mt * 16 + (lane & 15);
    int kbase = kt * 32 + (lane >> 4) * 8;
    unsigned int r[4];
    #pragma unroll
    for (int p = 0; p < 4; ++p) {
        unsigned int half[2];
        #pragma unroll
        for (int jj = 0; jj < 2; ++jj) {
            int k = kbase + 2 * p + jj;
            int t = k >> 6;
            int i = k & 63;
            half[jj] = f2bf(Wc[m * 448 + i * 7 + t]);
        }
        r[p] = half[0] | (half[1] << 16);
    }
    Ap[idx] = make_uint4(r[0], r[1], r[2], r[3]);
}

__global__ __launch_bounds__(256, 4) void fused_mfma_kernel(
    const float* __restrict__ x, const uint4* __restrict__ Ap,
    const float* __restrict__ p4w, float* __restrict__ out)
{
    // xT (bf16 staging, 21 KB) and convbuf (fp32, 33.8 KB) are never live
    // simultaneously: union them. LDS 33792 B -> 4 blocks/CU.
    __shared__ __attribute__((aligned(16))) char smem[SMEM_BYTES];
    unsigned short* xT = (unsigned short*)smem;
    float* convbuf = (float*)smem;

    // XCD-aware swizzle: xcd = b&7 (round-robin dispatch). Each XCD owns a
    // contiguous 16-row h-chunk per n, so epilogue tap rows (h-3,h-1,h+1)
    // hit the home XCD's L2 instead of re-fetching from HBM.
    const int b = blockIdx.x;
    const int xcd = b & 7;
    const int i_ = b >> 3;           // 0..511
    const int n = i_ >> 4;           // 0..31
    const int h = xcd * 16 + (i_ & 15);

    const int tid = threadIdx.x;
    const int wave = tid >> 6;
    const int lane = tid & 63;
    const int l16 = lane & 15;
    const int quad = lane >> 4;
    const float* xn = x + (size_t)n * CHW_;

    // ---- issue ALL 32 staging loads first (each one 256B coalesced) ----
    const float* xrow = xn + h * W_;
    float sv[4][8];
    #pragma unroll
    for (int p = 0; p < 4; ++p) {
        const int c0 = wave * 8 + (p >> 1) * 32;       // wave-uniform channel group
        const int w = lane + (p & 1) * 64;             // 0..127
        const float* src = xrow + (size_t)c0 * HW_ + w;
        #pragma unroll
        for (int i = 0; i < 8; ++i)
            sv[p][i] = src[(size_t)i * HW_];
    }

    // ---- afrag ring: 4-deep rolling prefetch (16 VGPRs vs 56 resident).
    // 1 L2-hit load per kt with 4-kt (~400 cyc) lookahead — covers L2 latency
    // (round 6's failure was 4 loads/kt at 1-deep = ~100 cyc lookahead).
    const uint4* Apl = Ap + wave * 64 + lane;
    uint4 aw[4];
    #pragma unroll
    for (int kt = 0; kt < 4; ++kt)
        aw[kt] = Apl[kt * 256];

    // ---- zero pad rows (rows 0..8 and 137..145), dword writes ----
    unsigned int* xz = (unsigned int*)xT;
    for (int i = tid; i < 648; i += 256) {
        int d = (i < 324) ? i : (4932 + (i - 324));
        xz[d] = 0u;
    }

    // ---- pack + conflict-free ds_write_b128 ----
    // Write bank-group = (w+9 + c0/8) & 7; 64 consecutive w -> 8 lanes/group.
    #pragma unroll
    for (int p = 0; p < 4; ++p) {
        const int c0 = wave * 8 + (p >> 1) * 32;
        const int w = lane + (p & 1) * 64;
        unsigned int pk[4];
        #pragma unroll
        for (int i = 0; i < 4; ++i)
            pk[i] = (unsigned int)f2bf(sv[p][2 * i]) |
                    ((unsigned int)f2bf(sv[p][2 * i + 1]) << 16);
        *(uint4*)&xT[(w + 9) * XT_STRIDE + c0] = make_uint4(pk[0], pk[1], pk[2], pk[3]);
    }

    // ---- HOISTED epilogue loads: taps + xv, reduced to t4 on arrival ----
    // These depend on nothing the K-loop produces. Issuing them here lets
    // their L2 latency overlap the staging drain instead of being exposed
    // after the K-loop. Long-lived: t4v (32) + xvv (32) regs through K-loop.
    const float p0 = p4w[0], p1 = p4w[1], p2 = p4w[2];
    const int h1 = (h - 1 + H_) & 127;
    const int hi = lane >> 5;           // 0..1
    const int w = (lane & 31) * 4;      // 0..124
    const int wsa = w + 2;              // <= 126, no wrap
    const int wsb = (w + 4) & 127;      // wraps only at w = 124

    float t4v[8][4];
    float4 xvv[8];
    #pragma unroll
    for (int j = 0; j < 8; ++j) {
        const int o_ = j * 2 + hi;               // 0..15
        const int o = wave * 16 + o_;
        const float* xc = xn + (size_t)o * HW_;
        xvv[j] = *(const float4*)(xc + h * W_ + w);
        float t4e[4] = {0.f, 0.f, 0.f, 0.f};
        #pragma unroll
        for (int k = 0; k < 3; ++k) {
            const int hh = h1 + 2 * k - 2;       // wave-uniform branch
            if (hh >= 0 && hh < H_) {
                const float pk_ = (k == 0) ? p0 : (k == 1) ? p1 : p2;
                const float* rowp = xc + hh * W_;
                float2 a = *(const float2*)(rowp + wsa);
                float2 b2 = *(const float2*)(rowp + wsb);
                t4e[0] += pk_ * a.x;  t4e[1] += pk_ * a.y;
                t4e[2] += pk_ * b2.x; t4e[3] += pk_ * b2.y;
            }
        }
        t4v[j][0] = t4e[0]; t4v[j][1] = t4e[1];
        t4v[j][2] = t4e[2]; t4v[j][3] = t4e[3];
    }

    __syncthreads();

    // ---- MFMA K-loop: O[o0+16][128] for o0 = wave*16 ----
    // B-read bank-group = (row + chunk) & 7: 8 lanes/group -> conflict-free.
    // Weight ring rolls: use aw[kt&3], refill with kt+4 (fully unrolled ->
    // static indices -> registers).
    floatx4 acc[8];
    #pragma unroll
    for (int nt = 0; nt < 8; ++nt) acc[nt] = (floatx4){0.f, 0.f, 0.f, 0.f};

    const int base_half = l16 * XT_STRIDE + quad * 8;
    #pragma unroll
    for (int kt = 0; kt < 14; ++kt) {
        bf16x8 av = __builtin_bit_cast(bf16x8, aw[kt & 3]);
        if (kt + 4 < 14)
            aw[kt & 3] = Apl[(kt + 4) * 256];
        int koff = (kt >> 1) * 3 * XT_STRIDE + (kt & 1) * 32;
        #pragma unroll
        for (int nt = 0; nt < 8; ++nt) {
            int off = base_half + koff + nt * 16 * XT_STRIDE;
            uint4 d = *(const uint4*)&xT[off];           // ds_read_b128, 16B-aligned
            bf16x8 bv = __builtin_bit_cast(bf16x8, d);
            acc[nt] = __builtin_amdgcn_mfma_f32_16x16x32_bf16(av, bv, acc[nt], 0, 0, 0);
        }
    }

    // xT is dead past here; convbuf aliases it — barrier before reuse.
    __syncthreads();

    // ---- scatter conv result into convbuf (wave-private region) ----
    // Banks: (16q + 4r + 16nt + l16) % 32 -> 2-way (free).
    // Same-wave ds_write -> ds_read is ordered by lgkmcnt; no extra barrier.
    float* cw = convbuf + wave * 16 * CB_STRIDE;
    #pragma unroll
    for (int nt = 0; nt < 8; ++nt) {
        #pragma unroll
        for (int r = 0; r < 4; ++r)
            cw[(quad * 4 + r) * CB_STRIDE + nt * 16 + l16] = acc[nt][r];
    }

    // ---- epilogue tail: conv from LDS (now 16B-aligned b128), fuse, store ----
    #pragma unroll
    for (int j = 0; j < 8; ++j) {
        const int o_ = j * 2 + hi;
        const int o = wave * 16 + o_;
        float4 cv = *(const float4*)&cw[o_ * CB_STRIDE + w];   // aligned: 132*4 % 16 == 0
        float ov[4];
        float xa[4] = {xvv[j].x, xvv[j].y, xvv[j].z, xvv[j].w};
        float ca[4] = {cv.x, cv.y, cv.z, cv.w};
        #pragma unroll
        for (int e = 0; e < 4; ++e)
            ov[e] = (xa[e] + ca[e]) * t4v[j][e];
        *(float4*)(out + (size_t)n * CHW_ + (size_t)o * HW_ + h * W_ + w) =
            make_float4(ov[0], ov[1], ov[2], ov[3]);
    }
}

extern "C" void kernel_launch(void* const* d_in, const int* in_sizes, int n_in,
                              void* d_out, int out_size, void* d_ws, size_t ws_size,
                              hipStream_t stream) {
    const float* x   = (const float*)d_in[0];
    const float* Wc  = (const float*)d_in[1];
    const float* p4w = (const float*)d_in[2];
    float* out       = (float*)d_out;
    uint4* Apack     = (uint4*)d_ws;   // 14*4*64*16 = 57344 B

    prepack_kernel<<<14, 256, 0, stream>>>(Wc, Apack);
    fused_mfma_kernel<<<N_ * H_, 256, 0, stream>>>(x, Apack, p4w, out);
}